// Round 1
// baseline (527.181 us; speedup 1.0000x reference)
//
#include <hip/hip_runtime.h>
#include <stdint.h>

typedef unsigned short u16;
typedef __attribute__((ext_vector_type(8))) short short8;
typedef __attribute__((ext_vector_type(4))) float f32x4;
typedef __attribute__((ext_vector_type(4))) unsigned short u16x4;

__device__ __forceinline__ u16 f2bf(float f) {
  uint32_t u = __float_as_uint(f);
  return (u16)((u + 0x7FFFu + ((u >> 16) & 1u)) >> 16);
}

__device__ __forceinline__ void gl2lds16(const u16* g, u16* l) {
  __builtin_amdgcn_global_load_lds(
      (const __attribute__((address_space(1))) unsigned int*)g,
      (__attribute__((address_space(3))) unsigned int*)l, 16, 0, 0);
}

// ---------- convert + concat: kvin[b][t][e] bf16, t<2048 -> x, else latents ----------
__global__ __launch_bounds__(256) void conv_kvin(const float* __restrict__ x,
                                                 const float* __restrict__ lat,
                                                 u16* __restrict__ kvin) {
  const int64_t total8 = (int64_t)20480 * 1024 / 8;
  for (int64_t i = (int64_t)blockIdx.x * 256 + threadIdx.x; i < total8;
       i += (int64_t)gridDim.x * 256) {
    const int64_t e0 = i * 8;
    const int row = (int)(e0 >> 10);
    const int col = (int)(e0 & 1023);
    const int b = row / 2560;
    const int t = row - b * 2560;
    const float* src = (t < 2048)
        ? (x + ((int64_t)b * 2048 + t) * 1024 + col)
        : (lat + ((int64_t)b * 512 + (t - 2048)) * 1024 + col);
    const float4 v0 = *(const float4*)src;
    const float4 v1 = *(const float4*)(src + 4);
    union { u16 s[8]; short8 v; } pk;
    pk.s[0] = f2bf(v0.x); pk.s[1] = f2bf(v0.y); pk.s[2] = f2bf(v0.z); pk.s[3] = f2bf(v0.w);
    pk.s[4] = f2bf(v1.x); pk.s[5] = f2bf(v1.y); pk.s[6] = f2bf(v1.z); pk.s[7] = f2bf(v1.w);
    *(short8*)(kvin + e0) = pk.v;
  }
}

// ---------- transpose + convert weights: dst[n][k] = bf16(src[k][n]) ----------
__global__ __launch_bounds__(256) void convT(const float* __restrict__ src,
                                             u16* __restrict__ dst, int K, int N) {
  __shared__ float tile[32][33];
  const int kb = blockIdx.x * 32, nb = blockIdx.y * 32;
  const int tx = threadIdx.x & 31, ty = threadIdx.x >> 5;
  #pragma unroll
  for (int i = 0; i < 4; i++)
    tile[ty + i * 8][tx] = src[(int64_t)(kb + ty + i * 8) * N + nb + tx];
  __syncthreads();
  #pragma unroll
  for (int i = 0; i < 4; i++)
    dst[(int64_t)(nb + ty + i * 8) * K + kb + tx] = f2bf(tile[tx][ty + i * 8]);
}

// ---------- 128x128 bf16 MFMA GEMM, K=1024, B given as Bt[N][K] ----------
// MODE 0: q-GEMM   (A rows mapped into latent part of kvin, out bf16 * 0.125)
// MODE 1: kv-GEMM  (out col<1024 -> kbuf row-major bf16; col>=1024 -> vT transposed bf16)
// MODE 2: out-GEMM (A already bf16 flat, out fp32)
template <int MODE>
__global__ __launch_bounds__(256) void gemm128(const u16* __restrict__ A0,
                                               const u16* __restrict__ Bt,
                                               void* __restrict__ C0,
                                               void* __restrict__ C1) {
  __shared__ u16 As[128 * 64];
  __shared__ u16 Bs[128 * 64];
  const int tid = threadIdx.x;
  const int lane = tid & 63, wave = tid >> 6;
  const int l16 = lane & 15, g4 = lane >> 4;
  const int bm = blockIdx.x, bn = blockIdx.y;

  const u16* Arow;
  if (MODE == 0) {
    const int b = bm >> 2;  // 4 blocks of 128 rows per batch of 512 latent rows
    Arow = A0 + ((int64_t)b * 2560 + 2048 + (int64_t)(bm & 3) * 128) * 1024;
  } else {
    Arow = A0 + (int64_t)bm * 128 * 1024;
  }
  const u16* Brow = Bt + (int64_t)bn * 128 * 1024;

  const int wm = wave >> 1, wn = wave & 1;
  const int srow = lane >> 3;       // 0..7 row within 8-row chunk
  const int scol = (lane & 7) * 8;  // k element offset (16B)

  f32x4 acc[4][4];
  #pragma unroll
  for (int m = 0; m < 4; m++)
    #pragma unroll
    for (int n = 0; n < 4; n++)
      acc[m][n] = (f32x4){0.f, 0.f, 0.f, 0.f};

  for (int kt = 0; kt < 1024; kt += 64) {
    #pragma unroll
    for (int i = 0; i < 4; i++) {
      const int c = wave * 4 + i;  // 16 chunks of 8 rows x 64 k
      gl2lds16(Arow + (int64_t)(c * 8 + srow) * 1024 + kt + scol, &As[c * 512]);
      gl2lds16(Brow + (int64_t)(c * 8 + srow) * 1024 + kt + scol, &Bs[c * 512]);
    }
    __syncthreads();
    #pragma unroll
    for (int kk = 0; kk < 2; kk++) {
      short8 af[4], bfr[4];
      #pragma unroll
      for (int m = 0; m < 4; m++)
        af[m] = *(const short8*)&As[(wm * 64 + m * 16 + l16) * 64 + kk * 32 + g4 * 8];
      #pragma unroll
      for (int n = 0; n < 4; n++)
        bfr[n] = *(const short8*)&Bs[(wn * 64 + n * 16 + l16) * 64 + kk * 32 + g4 * 8];
      #pragma unroll
      for (int m = 0; m < 4; m++)
        #pragma unroll
        for (int n = 0; n < 4; n++)
          acc[m][n] = __builtin_amdgcn_mfma_f32_16x16x32_bf16(af[m], bfr[n], acc[m][n], 0, 0, 0);
    }
    __syncthreads();
  }

  const int r0 = bm * 128 + wm * 64;
  const int c0 = bn * 128 + wn * 64;
  #pragma unroll
  for (int m = 0; m < 4; m++) {
    #pragma unroll
    for (int n = 0; n < 4; n++) {
      const int col = c0 + n * 16 + l16;
      if (MODE == 1 && col >= 1024) {
        // V part: store transposed vT[(b*1024 + dn)][t], 4 consecutive t packed
        const int rbase = r0 + m * 16 + g4 * 4;
        const int b = rbase / 2560;
        const int t = rbase - b * 2560;
        u16x4 vv;
        vv[0] = f2bf(acc[m][n][0]); vv[1] = f2bf(acc[m][n][1]);
        vv[2] = f2bf(acc[m][n][2]); vv[3] = f2bf(acc[m][n][3]);
        *(u16x4*)((u16*)C1 + ((int64_t)b * 1024 + (col - 1024)) * 2560 + t) = vv;
      } else {
        #pragma unroll
        for (int j = 0; j < 4; j++) {
          const int row = r0 + m * 16 + g4 * 4 + j;
          const float v = acc[m][n][j];
          if (MODE == 2)      ((float*)C0)[(int64_t)row * 1024 + col] = v;
          else if (MODE == 0) ((u16*)C0)[(int64_t)row * 1024 + col] = f2bf(v * 0.125f);
          else                ((u16*)C0)[(int64_t)row * 1024 + col] = f2bf(v);
        }
      }
    }
  }
}

// ---------- flash attention: 4 independent waves/block, 32 q-rows/wave, KVBLK=32 ----------
__global__ __launch_bounds__(256) void attn_kernel(const u16* __restrict__ q,
                                                   const u16* __restrict__ kbuf,
                                                   const u16* __restrict__ vT,
                                                   const float* __restrict__ mask_x,
                                                   const float* __restrict__ mask_lat,
                                                   u16* __restrict__ y) {
  __shared__ u16 P[4][32][40];  // per-wave P tile, padded stride
  const int bh = blockIdx.x;    // 0..127  (same (b,h) -> same XCD for all 4 q-blocks)
  const int qb = blockIdx.y;    // 0..3
  const int b = bh >> 4, h = bh & 15;
  const int tid = threadIdx.x, lane = tid & 63, wave = tid >> 6;
  const int l16 = lane & 15, g4 = lane >> 4;
  const int qrow0 = qb * 128 + wave * 32;

  short8 qf[2][2];
  #pragma unroll
  for (int m = 0; m < 2; m++)
    #pragma unroll
    for (int kk = 0; kk < 2; kk++)
      qf[m][kk] = *(const short8*)&q[((int64_t)(b * 512 + qrow0 + m * 16 + l16)) * 1024 +
                                     h * 64 + kk * 32 + g4 * 8];
  float qm[2][4];
  #pragma unroll
  for (int m = 0; m < 2; m++)
    #pragma unroll
    for (int j = 0; j < 4; j++)
      qm[m][j] = mask_lat[b * 512 + qrow0 + m * 16 + g4 * 4 + j];

  float mrun[2][4], lsum[2][4];
  f32x4 yacc[2][4];
  #pragma unroll
  for (int m = 0; m < 2; m++) {
    #pragma unroll
    for (int j = 0; j < 4; j++) { mrun[m][j] = -3.4028235e38f; lsum[m][j] = 0.f; }
    #pragma unroll
    for (int d0 = 0; d0 < 4; d0++) yacc[m][d0] = (f32x4){0.f, 0.f, 0.f, 0.f};
  }

  for (int t0 = 0; t0 < 2560; t0 += 32) {
    short8 kf[2][2];
    #pragma unroll
    for (int tf = 0; tf < 2; tf++)
      #pragma unroll
      for (int kk = 0; kk < 2; kk++)
        kf[tf][kk] = *(const short8*)&kbuf[((int64_t)(b * 2560 + t0 + tf * 16 + l16)) * 1024 +
                                           h * 64 + kk * 32 + g4 * 8];
    float kvm[2];
    #pragma unroll
    for (int tf = 0; tf < 2; tf++) {
      const int t = t0 + tf * 16 + l16;
      kvm[tf] = (t < 2048) ? mask_x[b * 2048 + t] : mask_lat[b * 512 + t - 2048];
    }
    short8 vf[4];  // issued early so latency hides under QK^T + softmax
    #pragma unroll
    for (int d0 = 0; d0 < 4; d0++)
      vf[d0] = *(const short8*)&vT[((int64_t)(b * 1024 + h * 64 + d0 * 16 + l16)) * 2560 +
                                   t0 + g4 * 8];

    f32x4 s[2][2];
    #pragma unroll
    for (int m = 0; m < 2; m++)
      #pragma unroll
      for (int tf = 0; tf < 2; tf++) {
        s[m][tf] = (f32x4){0.f, 0.f, 0.f, 0.f};
        #pragma unroll
        for (int kk = 0; kk < 2; kk++)
          s[m][tf] = __builtin_amdgcn_mfma_f32_16x16x32_bf16(qf[m][kk], kf[tf][kk], s[m][tf], 0, 0, 0);
      }

    #pragma unroll
    for (int m = 0; m < 2; m++) {
      #pragma unroll
      for (int j = 0; j < 4; j++) {
        float s0 = s[m][0][j] + (1.0f - qm[m][j] * kvm[0]) * (-3.4028235e38f);
        float s1 = s[m][1][j] + (1.0f - qm[m][j] * kvm[1]) * (-3.4028235e38f);
        float mx = fmaxf(s0, s1);
        mx = fmaxf(mx, __shfl_xor(mx, 1));
        mx = fmaxf(mx, __shfl_xor(mx, 2));
        mx = fmaxf(mx, __shfl_xor(mx, 4));
        mx = fmaxf(mx, __shfl_xor(mx, 8));
        const float nm = fmaxf(mrun[m][j], mx);
        const float alpha = __expf(mrun[m][j] - nm);
        mrun[m][j] = nm;
        const float p0 = __expf(s0 - nm);
        const float p1 = __expf(s1 - nm);
        float rs = p0 + p1;
        rs += __shfl_xor(rs, 1);
        rs += __shfl_xor(rs, 2);
        rs += __shfl_xor(rs, 4);
        rs += __shfl_xor(rs, 8);
        lsum[m][j] = lsum[m][j] * alpha + rs;
        #pragma unroll
        for (int d0 = 0; d0 < 4; d0++) yacc[m][d0][j] *= alpha;
        P[wave][m * 16 + g4 * 4 + j][l16] = f2bf(p0);
        P[wave][m * 16 + g4 * 4 + j][16 + l16] = f2bf(p1);
      }
    }
    short8 pf[2];
    #pragma unroll
    for (int m = 0; m < 2; m++)
      pf[m] = *(const short8*)&P[wave][m * 16 + l16][g4 * 8];
    #pragma unroll
    for (int m = 0; m < 2; m++)
      #pragma unroll
      for (int d0 = 0; d0 < 4; d0++)
        yacc[m][d0] = __builtin_amdgcn_mfma_f32_16x16x32_bf16(pf[m], vf[d0], yacc[m][d0], 0, 0, 0);
  }

  #pragma unroll
  for (int m = 0; m < 2; m++)
    #pragma unroll
    for (int d0 = 0; d0 < 4; d0++)
      #pragma unroll
      for (int j = 0; j < 4; j++) {
        const float val = yacc[m][d0][j] / lsum[m][j];
        y[((int64_t)(b * 512 + qrow0 + m * 16 + g4 * 4 + j)) * 1024 +
          h * 64 + d0 * 16 + l16] = f2bf(val);
      }
}

extern "C" void kernel_launch(void* const* d_in, const int* in_sizes, int n_in,
                              void* d_out, int out_size, void* d_ws, size_t ws_size,
                              hipStream_t stream) {
  const float* x        = (const float*)d_in[0];
  const float* lat      = (const float*)d_in[1];
  const float* mask_x   = (const float*)d_in[2];
  const float* mask_lat = (const float*)d_in[3];
  const float* Wq       = (const float*)d_in[4];
  const float* Wkv      = (const float*)d_in[5];
  const float* Wp       = (const float*)d_in[6];

  // workspace carve (bf16 = u16), total ~143 MB
  u16* kvin = (u16*)d_ws;                         // [8][2560][1024]
  u16* WqT  = kvin + (int64_t)20480 * 1024;       // [1024][1024]
  u16* WkvT = WqT  + (int64_t)1024 * 1024;        // [2048][1024]
  u16* WpT  = WkvT + (int64_t)2048 * 1024;        // [1024][1024]
  u16* qb   = WpT  + (int64_t)1024 * 1024;        // [4096][1024]
  u16* kb   = qb   + (int64_t)4096 * 1024;        // [8*2560][1024]
  u16* vT   = kb   + (int64_t)20480 * 1024;       // [8*1024][2560]
  u16* yb   = kvin;                               // reuse kvin after GEMMs: [4096][1024]

  conv_kvin<<<2560, 256, 0, stream>>>(x, lat, kvin);
  convT<<<dim3(32, 32), 256, 0, stream>>>(Wq, WqT, 1024, 1024);
  convT<<<dim3(32, 64), 256, 0, stream>>>(Wkv, WkvT, 1024, 2048);
  convT<<<dim3(32, 32), 256, 0, stream>>>(Wp, WpT, 1024, 1024);

  gemm128<0><<<dim3(32, 8), 256, 0, stream>>>(kvin, WqT, qb, nullptr);
  gemm128<1><<<dim3(160, 16), 256, 0, stream>>>(kvin, WkvT, kb, vT);
  attn_kernel<<<dim3(128, 4), 256, 0, stream>>>(qb, kb, vT, mask_x, mask_lat, yb);
  gemm128<2><<<dim3(32, 8), 256, 0, stream>>>(yb, WpT, d_out, nullptr);
}

// Round 4
// 488.688 us; speedup vs baseline: 1.0788x; 1.0788x over previous
//
#include <hip/hip_runtime.h>
#include <stdint.h>

typedef unsigned short u16;
typedef __attribute__((ext_vector_type(8))) short short8;
typedef __attribute__((ext_vector_type(4))) float f32x4;
typedef __attribute__((ext_vector_type(16))) float f32x16;
typedef __attribute__((ext_vector_type(4))) unsigned short u16x4;

__device__ __forceinline__ u16 f2bf(float f) {
  uint32_t u = __float_as_uint(f);
  return (u16)((u + 0x7FFFu + ((u >> 16) & 1u)) >> 16);
}

__device__ __forceinline__ void gl2lds16(const u16* g, u16* l) {
  __builtin_amdgcn_global_load_lds(
      (const __attribute__((address_space(1))) unsigned int*)g,
      (__attribute__((address_space(3))) unsigned int*)l, 16, 0, 0);
}

__device__ __forceinline__ float exp2fast(float x) {
#if __has_builtin(__builtin_amdgcn_exp2f)
  return __builtin_amdgcn_exp2f(x);
#else
  return exp2f(x);
#endif
}

__device__ __forceinline__ unsigned int cvtpk(float lo, float hi) {
  unsigned int r;
  asm("v_cvt_pk_bf16_f32 %0, %1, %2" : "=v"(r) : "v"(lo), "v"(hi));
  return r;
}

// cross-half (lane vs lane^32) combine helpers via permlane32_swap
__device__ __forceinline__ float halfmax(float x) {
  auto r = __builtin_amdgcn_permlane32_swap(__float_as_uint(x), __float_as_uint(x), false, false);
  return fmaxf(__uint_as_float(r[0]), __uint_as_float(r[1]));
}
__device__ __forceinline__ float halfadd(float x) {
  auto r = __builtin_amdgcn_permlane32_swap(__float_as_uint(x), __float_as_uint(x), false, false);
  return __uint_as_float(r[0]) + __uint_as_float(r[1]);
}

// ---------- convert + concat: kvin[b][t][e] bf16, t<2048 -> x, else latents ----------
__global__ __launch_bounds__(256) void conv_kvin(const float* __restrict__ x,
                                                 const float* __restrict__ lat,
                                                 u16* __restrict__ kvin) {
  const int64_t total8 = (int64_t)20480 * 1024 / 8;
  for (int64_t i = (int64_t)blockIdx.x * 256 + threadIdx.x; i < total8;
       i += (int64_t)gridDim.x * 256) {
    const int64_t e0 = i * 8;
    const int row = (int)(e0 >> 10);
    const int col = (int)(e0 & 1023);
    const int b = row / 2560;
    const int t = row - b * 2560;
    const float* src = (t < 2048)
        ? (x + ((int64_t)b * 2048 + t) * 1024 + col)
        : (lat + ((int64_t)b * 512 + (t - 2048)) * 1024 + col);
    const float4 v0 = *(const float4*)src;
    const float4 v1 = *(const float4*)(src + 4);
    union { u16 s[8]; short8 v; } pk;
    pk.s[0] = f2bf(v0.x); pk.s[1] = f2bf(v0.y); pk.s[2] = f2bf(v0.z); pk.s[3] = f2bf(v0.w);
    pk.s[4] = f2bf(v1.x); pk.s[5] = f2bf(v1.y); pk.s[6] = f2bf(v1.z); pk.s[7] = f2bf(v1.w);
    *(short8*)(kvin + e0) = pk.v;
  }
}

// ---------- mask -> additive bias over concatenated kv timeline ----------
__global__ __launch_bounds__(256) void prep_bias(const float* __restrict__ mask_x,
                                                 const float* __restrict__ mask_lat,
                                                 float* __restrict__ biasKV) {
  const int i = blockIdx.x * 256 + threadIdx.x;  // < 20480
  if (i >= 20480) return;
  const int b = i / 2560, t = i - b * 2560;
  const float m = (t < 2048) ? mask_x[b * 2048 + t] : mask_lat[b * 512 + t - 2048];
  biasKV[i] = (1.0f - m) * (-1.0e30f);
}

// ---------- transpose + convert weights: dst[n][k] = bf16(src[k][n]) ----------
__global__ __launch_bounds__(256) void convT(const float* __restrict__ src,
                                             u16* __restrict__ dst, int K, int N) {
  __shared__ float tile[32][33];
  const int kb = blockIdx.x * 32, nb = blockIdx.y * 32;
  const int tx = threadIdx.x & 31, ty = threadIdx.x >> 5;
  #pragma unroll
  for (int i = 0; i < 4; i++)
    tile[ty + i * 8][tx] = src[(int64_t)(kb + ty + i * 8) * N + nb + tx];
  __syncthreads();
  #pragma unroll
  for (int i = 0; i < 4; i++)
    dst[(int64_t)(nb + ty + i * 8) * K + kb + tx] = f2bf(tile[tx][ty + i * 8]);
}

// ---------- 128x128 bf16 MFMA GEMM, K=1024, B given as Bt[N][K] ----------
// MODE 0: q-GEMM   (A rows = latent part of kvin; out bf16 * 0.125*log2e for exp2-domain softmax)
// MODE 1: kv-GEMM  (out col<1024 -> kbuf row-major bf16; col>=1024 -> vT transposed bf16)
// MODE 2: out-GEMM (A already bf16 flat, out fp32)
template <int MODE>
__global__ __launch_bounds__(256) void gemm128(const u16* __restrict__ A0,
                                               const u16* __restrict__ Bt,
                                               void* __restrict__ C0,
                                               void* __restrict__ C1) {
  __shared__ u16 As[128 * 64];
  __shared__ u16 Bs[128 * 64];
  const int tid = threadIdx.x;
  const int lane = tid & 63, wave = tid >> 6;
  const int l16 = lane & 15, g4 = lane >> 4;
  const int bm = blockIdx.x, bn = blockIdx.y;

  const u16* Arow;
  if (MODE == 0) {
    const int b = bm >> 2;
    Arow = A0 + ((int64_t)b * 2560 + 2048 + (int64_t)(bm & 3) * 128) * 1024;
  } else {
    Arow = A0 + (int64_t)bm * 128 * 1024;
  }
  const u16* Brow = Bt + (int64_t)bn * 128 * 1024;

  const int wm = wave >> 1, wn = wave & 1;
  const int srow = lane >> 3;
  const int scol = (lane & 7) * 8;

  f32x4 acc[4][4];
  #pragma unroll
  for (int m = 0; m < 4; m++)
    #pragma unroll
    for (int n = 0; n < 4; n++)
      acc[m][n] = (f32x4){0.f, 0.f, 0.f, 0.f};

  for (int kt = 0; kt < 1024; kt += 64) {
    #pragma unroll
    for (int i = 0; i < 4; i++) {
      const int c = wave * 4 + i;
      gl2lds16(Arow + (int64_t)(c * 8 + srow) * 1024 + kt + scol, &As[c * 512]);
      gl2lds16(Brow + (int64_t)(c * 8 + srow) * 1024 + kt + scol, &Bs[c * 512]);
    }
    __syncthreads();
    #pragma unroll
    for (int kk = 0; kk < 2; kk++) {
      short8 af[4], bfr[4];
      #pragma unroll
      for (int m = 0; m < 4; m++)
        af[m] = *(const short8*)&As[(wm * 64 + m * 16 + l16) * 64 + kk * 32 + g4 * 8];
      #pragma unroll
      for (int n = 0; n < 4; n++)
        bfr[n] = *(const short8*)&Bs[(wn * 64 + n * 16 + l16) * 64 + kk * 32 + g4 * 8];
      #pragma unroll
      for (int m = 0; m < 4; m++)
        #pragma unroll
        for (int n = 0; n < 4; n++)
          acc[m][n] = __builtin_amdgcn_mfma_f32_16x16x32_bf16(af[m], bfr[n], acc[m][n], 0, 0, 0);
    }
    __syncthreads();
  }

  const int r0 = bm * 128 + wm * 64;
  const int c0 = bn * 128 + wn * 64;
  #pragma unroll
  for (int m = 0; m < 4; m++) {
    #pragma unroll
    for (int n = 0; n < 4; n++) {
      const int col = c0 + n * 16 + l16;
      if (MODE == 1 && col >= 1024) {
        const int rbase = r0 + m * 16 + g4 * 4;
        const int b = rbase / 2560;
        const int t = rbase - b * 2560;
        u16x4 vv;
        vv[0] = f2bf(acc[m][n][0]); vv[1] = f2bf(acc[m][n][1]);
        vv[2] = f2bf(acc[m][n][2]); vv[3] = f2bf(acc[m][n][3]);
        *(u16x4*)((u16*)C1 + ((int64_t)b * 1024 + (col - 1024)) * 2560 + t) = vv;
      } else {
        #pragma unroll
        for (int j = 0; j < 4; j++) {
          const int row = r0 + m * 16 + g4 * 4 + j;
          const float v = acc[m][n][j];
          if (MODE == 2)      ((float*)C0)[(int64_t)row * 1024 + col] = v;
          else if (MODE == 0) ((u16*)C0)[(int64_t)row * 1024 + col] = f2bf(v * 0.18033688f);
          else                ((u16*)C0)[(int64_t)row * 1024 + col] = f2bf(v);
        }
      }
    }
  }
}

// ---------- flash attention v2: swapped-operand 32x32 MFMA, in-register softmax ----------
// 4 waves/block, 32 q-rows/wave, KVBLK=32, no LDS, no barriers.
__global__ __launch_bounds__(256, 2) void attn2(const u16* __restrict__ q,
                                                const u16* __restrict__ kbuf,
                                                const u16* __restrict__ vT,
                                                const float* __restrict__ biasKV,
                                                u16* __restrict__ y) {
  // XCD-aware swizzle: the 4 q-blocks of one (b,h) land on one XCD
  const int id = blockIdx.x;           // 0..511
  const int xcd = id & 7, rest = id >> 3;
  const int bh = xcd * 16 + (rest >> 2);  // 0..127
  const int qb = rest & 3;
  const int b = bh >> 4, h = bh & 15;
  const int lane = threadIdx.x & 63, wave = threadIdx.x >> 6;
  const int l32 = lane & 31, hi = lane >> 5;
  const int q0 = qb * 128 + wave * 32;

  // Q^T B-fragments: col q = l32, d = c*16 + hi*8 + j   (q pre-scaled by 0.125*log2e)
  short8 qf[4];
  const u16* qrow = q + ((int64_t)(b * 512 + q0 + l32)) * 1024 + h * 64;
  #pragma unroll
  for (int c = 0; c < 4; c++)
    qf[c] = *(const short8*)(qrow + c * 16 + hi * 8);

  float mrun = -3.0e38f, lsum = 0.f;
  f32x16 yacc0, yacc1;
  #pragma unroll
  for (int i = 0; i < 16; i++) { yacc0[i] = 0.f; yacc1[i] = 0.f; }

  const u16* kbase = kbuf + ((int64_t)(b * 2560 + l32)) * 1024 + h * 64;
  const u16* vbase = vT + ((int64_t)(b * 1024 + h * 64 + l32)) * 2560;
  const float* bbase = biasKV + b * 2560;

  for (int t0 = 0; t0 < 2560; t0 += 32) {
    // K A-fragments: row t = t0 + l32, d = c*16 + hi*8 + j
    short8 kf[4];
    #pragma unroll
    for (int c = 0; c < 4; c++)
      kf[c] = *(const short8*)(kbase + (int64_t)t0 * 1024 + c * 16 + hi * 8);
    // V^T A-fragments: row d = db*32 + l32, t = t0 + ks*16 + hi*8 + j
    short8 vf[2][2];
    #pragma unroll
    for (int db = 0; db < 2; db++)
      #pragma unroll
      for (int ks = 0; ks < 2; ks++)
        vf[db][ks] = *(const short8*)(vbase + (int64_t)db * 32 * 2560 + t0 + ks * 16 + hi * 8);
    // mask bias, float4 per reg-group g: t = t0 + g*8 + 4*hi + (r&3)
    float4 bb[4];
    #pragma unroll
    for (int g = 0; g < 4; g++)
      bb[g] = *(const float4*)(bbase + t0 + g * 8 + hi * 4);

    // S^T[k][q] = sum_d K[k][d] * Q^T[d][q]
    f32x16 S;
    #pragma unroll
    for (int i = 0; i < 16; i++) S[i] = 0.f;
    #pragma unroll
    for (int c = 0; c < 4; c++)
      S = __builtin_amdgcn_mfma_f32_32x32x16_bf16(kf[c], qf[c], S, 0, 0, 0);

    float t[16];
    #pragma unroll
    for (int r = 0; r < 16; r++) t[r] = S[r] + bb[r >> 2][r & 3];

    // row max: in-register tree + one cross-half swap
    float m01 = fmaxf(t[0], t[1]),  m23 = fmaxf(t[2], t[3]);
    float m45 = fmaxf(t[4], t[5]),  m67 = fmaxf(t[6], t[7]);
    float m89 = fmaxf(t[8], t[9]),  mab = fmaxf(t[10], t[11]);
    float mcd = fmaxf(t[12], t[13]), mef = fmaxf(t[14], t[15]);
    float tm = fmaxf(fmaxf(fmaxf(m01, m23), fmaxf(m45, m67)),
                     fmaxf(fmaxf(m89, mab), fmaxf(mcd, mef)));
    tm = halfmax(tm);

    // defer-max: rescale only when the running max grew past threshold (log2 units)
    if (__any(tm > mrun + 8.f)) {
      const float nm = fmaxf(mrun, tm);
      const float alpha = exp2fast(mrun - nm);
      mrun = nm;
      lsum *= alpha;
      #pragma unroll
      for (int i = 0; i < 16; i++) { yacc0[i] *= alpha; yacc1[i] *= alpha; }
    }

    float p[16];
    #pragma unroll
    for (int r = 0; r < 16; r++) p[r] = exp2fast(t[r] - mrun);

    float ps = ((p[0] + p[1]) + (p[2] + p[3])) + ((p[4] + p[5]) + (p[6] + p[7]));
    ps += ((p[8] + p[9]) + (p[10] + p[11])) + ((p[12] + p[13]) + (p[14] + p[15]));
    lsum += halfadd(ps);

    // P^T B-fragments via cvt_pk + permlane32_swap (T12): 8 cvt + 4 swaps -> 8 words
    union PA { unsigned int w[4]; short8 v; } pa0, pa1;
    {
      auto r0 = __builtin_amdgcn_permlane32_swap(cvtpk(p[0], p[1]), cvtpk(p[4], p[5]), false, false);
      pa0.w[0] = r0[0]; pa0.w[2] = r0[1];
      auto r1 = __builtin_amdgcn_permlane32_swap(cvtpk(p[2], p[3]), cvtpk(p[6], p[7]), false, false);
      pa0.w[1] = r1[0]; pa0.w[3] = r1[1];
      auto r2 = __builtin_amdgcn_permlane32_swap(cvtpk(p[8], p[9]), cvtpk(p[12], p[13]), false, false);
      pa1.w[0] = r2[0]; pa1.w[2] = r2[1];
      auto r3 = __builtin_amdgcn_permlane32_swap(cvtpk(p[10], p[11]), cvtpk(p[14], p[15]), false, false);
      pa1.w[1] = r3[0]; pa1.w[3] = r3[1];
    }

    // Y^T[d][q] += V^T[d][k] * P^T[k][q]
    yacc0 = __builtin_amdgcn_mfma_f32_32x32x16_bf16(vf[0][0], pa0.v, yacc0, 0, 0, 0);
    yacc0 = __builtin_amdgcn_mfma_f32_32x32x16_bf16(vf[0][1], pa1.v, yacc0, 0, 0, 0);
    yacc1 = __builtin_amdgcn_mfma_f32_32x32x16_bf16(vf[1][0], pa0.v, yacc1, 0, 0, 0);
    yacc1 = __builtin_amdgcn_mfma_f32_32x32x16_bf16(vf[1][1], pa1.v, yacc1, 0, 0, 0);
  }

  const float inv = 1.0f / lsum;
  u16* yr = y + ((int64_t)(b * 512 + q0 + l32)) * 1024 + h * 64;
  #pragma unroll
  for (int g = 0; g < 4; g++) {
    u16x4 o0, o1;
    #pragma unroll
    for (int j = 0; j < 4; j++) {
      o0[j] = f2bf(yacc0[g * 4 + j] * inv);
      o1[j] = f2bf(yacc1[g * 4 + j] * inv);
    }
    *(u16x4*)(yr + g * 8 + hi * 4) = o0;
    *(u16x4*)(yr + 32 + g * 8 + hi * 4) = o1;
  }
}

extern "C" void kernel_launch(void* const* d_in, const int* in_sizes, int n_in,
                              void* d_out, int out_size, void* d_ws, size_t ws_size,
                              hipStream_t stream) {
  const float* x        = (const float*)d_in[0];
  const float* lat      = (const float*)d_in[1];
  const float* mask_x   = (const float*)d_in[2];
  const float* mask_lat = (const float*)d_in[3];
  const float* Wq       = (const float*)d_in[4];
  const float* Wkv      = (const float*)d_in[5];
  const float* Wp       = (const float*)d_in[6];

  // workspace carve (bf16 = u16), total ~143 MB
  u16* kvin = (u16*)d_ws;                         // [8][2560][1024]
  u16* WqT  = kvin + (int64_t)20480 * 1024;       // [1024][1024]
  u16* WkvT = WqT  + (int64_t)1024 * 1024;        // [2048][1024]
  u16* WpT  = WkvT + (int64_t)2048 * 1024;        // [1024][1024]
  u16* qb   = WpT  + (int64_t)1024 * 1024;        // [4096][1024]
  u16* kb   = qb   + (int64_t)4096 * 1024;        // [8*2560][1024]
  u16* vT   = kb   + (int64_t)20480 * 1024;       // [8*1024][2560]
  float* biasKV = (float*)(vT + (int64_t)20480 * 1024);  // [8][2560]
  u16* yb   = kvin;                               // reuse kvin after GEMMs

  conv_kvin<<<2560, 256, 0, stream>>>(x, lat, kvin);
  prep_bias<<<80, 256, 0, stream>>>(mask_x, mask_lat, biasKV);
  convT<<<dim3(32, 32), 256, 0, stream>>>(Wq, WqT, 1024, 1024);
  convT<<<dim3(32, 64), 256, 0, stream>>>(Wkv, WkvT, 1024, 2048);
  convT<<<dim3(32, 32), 256, 0, stream>>>(Wp, WpT, 1024, 1024);

  gemm128<0><<<dim3(32, 8), 256, 0, stream>>>(kvin, WqT, qb, nullptr);
  gemm128<1><<<dim3(160, 16), 256, 0, stream>>>(kvin, WkvT, kb, vT);
  attn2<<<512, 256, 0, stream>>>(qb, kb, vT, biasKV, yb);
  gemm128<2><<<dim3(32, 8), 256, 0, stream>>>(yb, WpT, d_out, nullptr);
}